// Round 10
// baseline (363.882 us; speedup 1.0000x reference)
//
#include <hip/hip_runtime.h>

#define HASH_BINS 100000
#define EMBD 64
#define BATCH 262144
#define BM 64
#define SA 264  // single act buffer stride (bf16 elems); 132 dw ≡ 4 mod 32 -> 2-way (free) read aliasing

typedef __attribute__((ext_vector_type(8))) short short8;
typedef __attribute__((ext_vector_type(4))) float floatx4;
typedef __attribute__((ext_vector_type(4))) unsigned short ushortx4;

static __device__ __forceinline__ unsigned short f2bf(float f) {
  unsigned u = __builtin_bit_cast(unsigned, f);
  u += 0x7fff + ((u >> 16) & 1);  // round-to-nearest-even
  return (unsigned short)(u >> 16);
}

// ---------------- prep: dest-major transposed/padded bf16 weights in ws ----------------
// layout: S@0, Kt@512 (128x128), W1t@33280 (224x128), W2t@90624 (256x224),
//         W3t@205312 (224x256), W4t@320000 (128x224)
__global__ void dfm_prep(const float* __restrict__ K, const float* __restrict__ W1,
                         const float* __restrict__ W2, const float* __restrict__ W3,
                         const float* __restrict__ W4,
                         float* __restrict__ S, unsigned short* __restrict__ Kt,
                         unsigned short* __restrict__ W1t, unsigned short* __restrict__ W2t,
                         unsigned short* __restrict__ W3t, unsigned short* __restrict__ W4t)
{
  int i = blockIdx.x * 256 + threadIdx.x;
  if (i < 4096) {                          // Kt [128][128] <- K[k][n]
    int n = i >> 5, k4 = (i & 31) * 4;
    ushortx4 h = { f2bf(K[(k4 + 0) * 128 + n]), f2bf(K[(k4 + 1) * 128 + n]),
                   f2bf(K[(k4 + 2) * 128 + n]), f2bf(K[(k4 + 3) * 128 + n]) };
    *(ushortx4*)&Kt[n * 128 + k4] = h;
  } else if ((i -= 4096) < 7168) {         // W1t [224][128] <- W1[k][n], n<200
    int n = i >> 5, k4 = (i & 31) * 4;
    ushortx4 h;
#pragma unroll
    for (int j = 0; j < 4; j++) h[j] = (n < 200) ? f2bf(W1[(k4 + j) * 200 + n]) : 0;
    *(ushortx4*)&W1t[n * 128 + k4] = h;
  } else if ((i -= 7168) < 14336) {        // W2t [256][224] <- W2[k][n], k<200
    int n = i / 56, k4 = (i - n * 56) * 4;
    ushortx4 h;
#pragma unroll
    for (int j = 0; j < 4; j++) h[j] = (k4 + j < 200) ? f2bf(W2[(k4 + j) * 256 + n]) : 0;
    *(ushortx4*)&W2t[n * 224 + k4] = h;
  } else if ((i -= 14336) < 14336) {       // W3t [224][256] <- W3[k][n], n<200
    int n = i >> 6, k4 = (i & 63) * 4;
    ushortx4 h;
#pragma unroll
    for (int j = 0; j < 4; j++) h[j] = (n < 200) ? f2bf(W3[(k4 + j) * 200 + n]) : 0;
    *(ushortx4*)&W3t[n * 256 + k4] = h;
  } else if ((i -= 14336) < 7168) {        // W4t [128][224] <- W4[k][n], k<200
    int n = i / 56, k4 = (i - n * 56) * 4;
    ushortx4 h;
#pragma unroll
    for (int j = 0; j < 4; j++) h[j] = (k4 + j < 200) ? f2bf(W4[(k4 + j) * 128 + n]) : 0;
    *(ushortx4*)&W4t[n * 224 + k4] = h;
  } else if ((i -= 7168) < 128) {          // S = rowsum(K^2)
    float s = 0.f;
    for (int j = 0; j < 128; j++) { float v = K[i * 128 + j]; s += v * v; }
    S[i] = s;
  }
}

// ---- prefetch ks=0 weight fragments (issued BEFORE a barrier) ----
template <int KP, int CH>
static __device__ __forceinline__ void wpref(const unsigned short* __restrict__ wt,
                                             int tileRow0, int m, int qd, short8* wpre)
{
#pragma unroll
  for (int n = 0; n < CH; n++)
    wpre[n] = *(const short8*)&wt[(tileRow0 + n * 16 + m) * KP + qd * 8];
}

// ---- MFMA pass: CH col-tiles x 4 row-tiles (ALL 64 rows), K=KP ----
// lane (m,qd,reg) holds D[neuron = tile*16 + qd*4 + reg][row = rt*16 + m].
template <int KP, int CH>
static __device__ __forceinline__ void mfma_pass_pre(const unsigned short* __restrict__ wt,
                                                     int tileRow0, const unsigned short* actIn,
                                                     int m, int qd, floatx4* acc,
                                                     const short8* wpre)
{
#pragma unroll
  for (int i = 0; i < CH * 4; i++) acc[i] = {0.f, 0.f, 0.f, 0.f};
  short8 a[4];
#pragma unroll
  for (int rt = 0; rt < 4; rt++)
    a[rt] = *(const short8*)&actIn[(rt * 16 + m) * SA + qd * 8];
#pragma unroll
  for (int n = 0; n < CH; n++)
#pragma unroll
    for (int rt = 0; rt < 4; rt++)
      acc[n * 4 + rt] = __builtin_amdgcn_mfma_f32_16x16x32_bf16(wpre[n], a[rt], acc[n * 4 + rt], 0, 0, 0);
#pragma unroll
  for (int ks = 1; ks < KP / 32; ks++) {
#pragma unroll
    for (int rt = 0; rt < 4; rt++)
      a[rt] = *(const short8*)&actIn[(rt * 16 + m) * SA + ks * 32 + qd * 8];
#pragma unroll
    for (int n = 0; n < CH; n++) {
      short8 w = *(const short8*)&wt[(tileRow0 + n * 16 + m) * KP + ks * 32 + qd * 8];
#pragma unroll
      for (int rt = 0; rt < 4; rt++)
        acc[n * 4 + rt] = __builtin_amdgcn_mfma_f32_16x16x32_bf16(w, a[rt], acc[n * 4 + rt], 0, 0, 0);
    }
  }
}

template <int KP, int CH>
static __device__ __forceinline__ void mfma_pass(const unsigned short* __restrict__ wt,
                                                 int tileRow0, const unsigned short* actIn,
                                                 int m, int qd, floatx4* acc)
{
#pragma unroll
  for (int i = 0; i < CH * 4; i++) acc[i] = {0.f, 0.f, 0.f, 0.f};
#pragma unroll
  for (int ks = 0; ks < KP / 32; ks++) {
    short8 a[4];
#pragma unroll
    for (int rt = 0; rt < 4; rt++)
      a[rt] = *(const short8*)&actIn[(rt * 16 + m) * SA + ks * 32 + qd * 8];
#pragma unroll
    for (int n = 0; n < CH; n++) {
      short8 w = *(const short8*)&wt[(tileRow0 + n * 16 + m) * KP + ks * 32 + qd * 8];
#pragma unroll
      for (int rt = 0; rt < 4; rt++)
        acc[n * 4 + rt] = __builtin_amdgcn_mfma_f32_16x16x32_bf16(w, a[rt], acc[n * 4 + rt], 0, 0, 0);
    }
  }
}

// ---- epilogue: bias + relu, packed 8B stores (in-place act, after read-barrier) ----
template <int CH>
static __device__ __forceinline__ void epilogue_relu(const float* __restrict__ bias,
                                                     int colBase, int nreal,
                                                     unsigned short* act,
                                                     int m, int qd, const floatx4* acc)
{
#pragma unroll
  for (int n = 0; n < CH; n++) {
    int col = colBase + n * 16 + qd * 4;
    float b0 = 0.f, b1 = 0.f, b2 = 0.f, b3 = 0.f;
    if (col < nreal) {
      float4 q = *(const float4*)(bias + col);
      b0 = q.x; b1 = q.y; b2 = q.z; b3 = q.w;
    }
#pragma unroll
    for (int rt = 0; rt < 4; rt++) {
      ushortx4 h = { f2bf(fmaxf(acc[n * 4 + rt][0] + b0, 0.f)),
                     f2bf(fmaxf(acc[n * 4 + rt][1] + b1, 0.f)),
                     f2bf(fmaxf(acc[n * 4 + rt][2] + b2, 0.f)),
                     f2bf(fmaxf(acc[n * 4 + rt][3] + b3, 0.f)) };
      *(ushortx4*)&act[(rt * 16 + m) * SA + col] = h;
    }
  }
}

// ---------------- fused main kernel ----------------
// 256 threads = 4 waves; each wave: ALL 64 rows x 1/4 of tiles (weight frags unique
// per wave, rt=4 hides each load). SINGLE in-place act buffer (~35.5 KB LDS) ->
// 4 blocks/CU; reg budget 128 (launch_bounds(256,4)), peak live acc = 16 floatx4.
__global__ __launch_bounds__(256, 4)
void dfm_main(const int* __restrict__ uidx, const int* __restrict__ iidx,
              const float* __restrict__ uemb, const float* __restrict__ iemb,
              const float* __restrict__ linw, const float* __restrict__ linb,
              const float* __restrict__ b1, const float* __restrict__ b2,
              const float* __restrict__ b3, const float* __restrict__ b4,
              const float* __restrict__ W5, const float* __restrict__ b5,
              const float* __restrict__ S, const unsigned short* __restrict__ Wc,
              const unsigned short* __restrict__ W2t, const unsigned short* __restrict__ W3t,
              const unsigned short* __restrict__ W4t,
              float* __restrict__ out)
{
  __shared__ unsigned short act[BM * SA];
  __shared__ float crosspart[4][BM];
  __shared__ float part[BM][4];
  __shared__ float qrow[BM];
  __shared__ float linrow[BM];

  const int t = threadIdx.x;
  const int lane = t & 63, wave = t >> 6;
  const int m = lane & 15, qd = lane >> 4;
  const int r = t >> 2, c = t & 3;                       // gather: 4 threads per row
  const int off = (wave < 2) ? wave * 4 : 8 + (wave - 2) * 3;  // 14-tile split {4,4,3,3}

  // ---- gather + linear + q-partials (q = sum x^2 * rowsum(K^2)) ----
  {
    int g = blockIdx.x * BM + r;
    int u = uidx[g], it = iidx[g];
    const float* up = uemb + (long)u * EMBD + c * 16;
    const float* ip = iemb + (long)it * EMBD + c * 16;
    float qp = 0.f;
#pragma unroll
    for (int j = 0; j < 16; j += 4) {
      float4 f = *(const float4*)(up + j);
      int col = c * 16 + j;
      float4 sv = *(const float4*)(S + col);
      ushortx4 h = {f2bf(f.x), f2bf(f.y), f2bf(f.z), f2bf(f.w)};
      *(ushortx4*)&act[r * SA + col] = h;
      qp += f.x * f.x * sv.x + f.y * f.y * sv.y + f.z * f.z * sv.z + f.w * f.w * sv.w;
    }
#pragma unroll
    for (int j = 0; j < 16; j += 4) {
      float4 f = *(const float4*)(ip + j);
      int col = 64 + c * 16 + j;
      float4 sv = *(const float4*)(S + col);
      ushortx4 h = {f2bf(f.x), f2bf(f.y), f2bf(f.z), f2bf(f.w)};
      *(ushortx4*)&act[r * SA + col] = h;
      qp += f.x * f.x * sv.x + f.y * f.y * sv.y + f.z * f.z * sv.z + f.w * f.w * sv.w;
    }
    // reduce q over the 4 c-lanes (consecutive lanes within the wave)
    qp += __shfl_xor(qp, 1, 64);
    qp += __shfl_xor(qp, 2, 64);
    if (c == 0) {
      qrow[r] = qp;
      linrow[r] = linw[u] + linw[HASH_BINS + it] + linb[0];
    }
  }
  short8 wpre[2];
  wpref<128, 2>(Wc, 2 * wave * 16, m, qd, wpre);  // cross ks=0 prefetch
  __syncthreads();  // B1: emb in act

  // ---- fused layer (K=128): cross tiles {2w,2w+1} + L1 tiles off..off+3 ----
  {
    floatx4 accC[8];
    mfma_pass_pre<128, 2>(Wc, 2 * wave * 16, act, m, qd, accC, wpre);
    float s[4];
#pragma unroll
    for (int rt = 0; rt < 4; rt++) {
      s[rt] = 0.f;
#pragma unroll
      for (int n = 0; n < 2; n++)
#pragma unroll
        for (int i = 0; i < 4; i++)
          s[rt] += accC[n * 4 + rt][i] * accC[n * 4 + rt][i];
      s[rt] += __shfl_xor(s[rt], 16, 64);
      s[rt] += __shfl_xor(s[rt], 32, 64);
    }
    if (qd == 0)
#pragma unroll
      for (int rt = 0; rt < 4; rt++)
        crosspart[wave][rt * 16 + m] = s[rt];

    floatx4 acc1[8];
    mfma_pass<128, 2>(Wc, 128 + off * 16, act, m, qd, acc1);
    if (wave < 2) {
      floatx4 acc2[8];
      mfma_pass<128, 2>(Wc, 128 + (off + 2) * 16, act, m, qd, acc2);
      __syncthreads();  // B2: all reads of emb done
      epilogue_relu<2>(b1, off * 16, 200, act, m, qd, acc1);
      epilogue_relu<2>(b1, (off + 2) * 16, 200, act, m, qd, acc2);
    } else {
      floatx4 acc2[4];
      mfma_pass<128, 1>(Wc, 128 + (off + 2) * 16, act, m, qd, acc2);
      __syncthreads();  // B2
      epilogue_relu<2>(b1, off * 16, 200, act, m, qd, acc1);
      epilogue_relu<1>(b1, (off + 2) * 16, 200, act, m, qd, acc2);
    }
  }
  wpref<224, 2>(W2t, wave * 64, m, qd, wpre);
  __syncthreads();  // B3: L1 out (224, zero-padded) in act

  // ---- W2: K=224, 16 tiles, 4 per wave (two CH=2 passes) ----
  {
    floatx4 acc1[8], acc2[8];
    mfma_pass_pre<224, 2>(W2t, wave * 64, act, m, qd, acc1, wpre);
    mfma_pass<224, 2>(W2t, wave * 64 + 32, act, m, qd, acc2);
    __syncthreads();  // B4: reads done
    epilogue_relu<2>(b2, wave * 64, 256, act, m, qd, acc1);
    epilogue_relu<2>(b2, wave * 64 + 32, 256, act, m, qd, acc2);
  }
  wpref<256, 2>(W3t, off * 16, m, qd, wpre);
  __syncthreads();  // B5: W2 out (256) in act

  // ---- W3: K=256, 14 tiles {4,4,3,3} ----
  {
    floatx4 acc1[8];
    mfma_pass_pre<256, 2>(W3t, off * 16, act, m, qd, acc1, wpre);
    if (wave < 2) {
      floatx4 acc2[8];
      mfma_pass<256, 2>(W3t, (off + 2) * 16, act, m, qd, acc2);
      __syncthreads();  // B6
      epilogue_relu<2>(b3, off * 16, 200, act, m, qd, acc1);
      epilogue_relu<2>(b3, (off + 2) * 16, 200, act, m, qd, acc2);
    } else {
      floatx4 acc2[4];
      mfma_pass<256, 1>(W3t, (off + 2) * 16, act, m, qd, acc2);
      __syncthreads();  // B6
      epilogue_relu<2>(b3, off * 16, 200, act, m, qd, acc1);
      epilogue_relu<1>(b3, (off + 2) * 16, 200, act, m, qd, acc2);
    }
  }
  wpref<224, 2>(W4t, wave * 32, m, qd, wpre);
  __syncthreads();  // B7: W3 out (224, zero-padded) in act

  // ---- W4 + W5 fold in registers: wave owns neurons 32w..32w+31 ----
  {
    floatx4 acc[8];
    mfma_pass_pre<224, 2>(W4t, wave * 32, act, m, qd, acc, wpre);
#pragma unroll
    for (int rt = 0; rt < 4; rt++) {
      float s = 0.f;
#pragma unroll
      for (int n = 0; n < 2; n++) {
        int nb = wave * 32 + n * 16 + qd * 4;
        float4 w5q = *(const float4*)(W5 + nb);
        float4 b4q = *(const float4*)(b4 + nb);
        s += fmaxf(acc[n * 4 + rt][0] + b4q.x, 0.f) * w5q.x +
             fmaxf(acc[n * 4 + rt][1] + b4q.y, 0.f) * w5q.y +
             fmaxf(acc[n * 4 + rt][2] + b4q.z, 0.f) * w5q.z +
             fmaxf(acc[n * 4 + rt][3] + b4q.w, 0.f) * w5q.w;
      }
      s += __shfl_xor(s, 16, 64);
      s += __shfl_xor(s, 32, 64);
      if (qd == 0) part[rt * 16 + m][wave] = s;
    }
  }
  __syncthreads();  // B8: partials ready

  // ---- combine + sigmoid ----
  if (t < BM) {
    float xk2 = crosspart[0][t] + crosspart[1][t] + crosspart[2][t] + crosspart[3][t];
    float dnn = part[t][0] + part[t][1] + part[t][2] + part[t][3];
    const float inv = 0.5f / 128.f;
    float logit = linrow[t] + inv * (xk2 - qrow[t]) + dnn + b5[0];
    out[blockIdx.x * BM + t] = 1.f / (1.f + expf(-logit));
  }
}

extern "C" void kernel_launch(void* const* d_in, const int* in_sizes, int n_in,
                              void* d_out, int out_size, void* d_ws, size_t ws_size,
                              hipStream_t stream)
{
  const int*   uidx = (const int*)d_in[0];
  const int*   iidx = (const int*)d_in[1];
  const float* uemb = (const float*)d_in[2];
  const float* iemb = (const float*)d_in[3];
  const float* linw = (const float*)d_in[4];
  const float* linb = (const float*)d_in[5];
  const float* K    = (const float*)d_in[6];
  const float* W1   = (const float*)d_in[7];
  const float* b1   = (const float*)d_in[8];
  const float* W2   = (const float*)d_in[9];
  const float* b2   = (const float*)d_in[10];
  const float* W3   = (const float*)d_in[11];
  const float* b3   = (const float*)d_in[12];
  const float* W4   = (const float*)d_in[13];
  const float* b4   = (const float*)d_in[14];
  const float* W5   = (const float*)d_in[15];
  const float* b5   = (const float*)d_in[16];

  char* w = (char*)d_ws;
  float* S = (float*)w;
  unsigned short* Kt  = (unsigned short*)(w + 512);
  unsigned short* W1t = (unsigned short*)(w + 33280);
  unsigned short* W2t = (unsigned short*)(w + 90624);
  unsigned short* W3t = (unsigned short*)(w + 205312);
  unsigned short* W4t = (unsigned short*)(w + 320000);
  float* out = (float*)d_out;

  dfm_prep<<<185, 256, 0, stream>>>(K, W1, W2, W3, W4, S, Kt, W1t, W2t, W3t, W4t);
  dfm_main<<<BATCH / BM, 256, 0, stream>>>(uidx, iidx, uemb, iemb, linw, linb,
                                           b1, b2, b3, b4, W5, b5,
                                           S, Kt, W2t, W3t, W4t, out);
}

// Round 11
// 277.055 us; speedup vs baseline: 1.3134x; 1.3134x over previous
//
#include <hip/hip_runtime.h>

#define HASH_BINS 100000
#define EMBD 64
#define BATCH 262144
#define BM 64
#define SA 264  // act buffer A stride (bf16 elems)
#define SB 232  // act buffer B stride (bf16 elems)

typedef __attribute__((ext_vector_type(8))) short short8;
typedef __attribute__((ext_vector_type(4))) float floatx4;
typedef __attribute__((ext_vector_type(4))) unsigned short ushortx4;

static __device__ __forceinline__ unsigned short f2bf(float f) {
  unsigned u = __builtin_bit_cast(unsigned, f);
  u += 0x7fff + ((u >> 16) & 1);  // round-to-nearest-even
  return (unsigned short)(u >> 16);
}

// ---------------- prep: dest-major transposed/padded bf16 weights in ws ----------------
// layout: S@0, Kt@512 (128x128), W1t@33280 (224x128), W2t@90624 (256x224),
//         W3t@205312 (224x256), W4t@320000 (128x224)
__global__ void dfm_prep(const float* __restrict__ K, const float* __restrict__ W1,
                         const float* __restrict__ W2, const float* __restrict__ W3,
                         const float* __restrict__ W4,
                         float* __restrict__ S, unsigned short* __restrict__ Kt,
                         unsigned short* __restrict__ W1t, unsigned short* __restrict__ W2t,
                         unsigned short* __restrict__ W3t, unsigned short* __restrict__ W4t)
{
  int i = blockIdx.x * 256 + threadIdx.x;
  if (i < 4096) {                          // Kt [128][128] <- K[k][n]
    int n = i >> 5, k4 = (i & 31) * 4;
    ushortx4 h = { f2bf(K[(k4 + 0) * 128 + n]), f2bf(K[(k4 + 1) * 128 + n]),
                   f2bf(K[(k4 + 2) * 128 + n]), f2bf(K[(k4 + 3) * 128 + n]) };
    *(ushortx4*)&Kt[n * 128 + k4] = h;
  } else if ((i -= 4096) < 7168) {         // W1t [224][128] <- W1[k][n], n<200
    int n = i >> 5, k4 = (i & 31) * 4;
    ushortx4 h;
#pragma unroll
    for (int j = 0; j < 4; j++) h[j] = (n < 200) ? f2bf(W1[(k4 + j) * 200 + n]) : 0;
    *(ushortx4*)&W1t[n * 128 + k4] = h;
  } else if ((i -= 7168) < 14336) {        // W2t [256][224] <- W2[k][n], k<200
    int n = i / 56, k4 = (i - n * 56) * 4;
    ushortx4 h;
#pragma unroll
    for (int j = 0; j < 4; j++) h[j] = (k4 + j < 200) ? f2bf(W2[(k4 + j) * 256 + n]) : 0;
    *(ushortx4*)&W2t[n * 224 + k4] = h;
  } else if ((i -= 14336) < 14336) {       // W3t [224][256] <- W3[k][n], n<200
    int n = i >> 6, k4 = (i & 63) * 4;
    ushortx4 h;
#pragma unroll
    for (int j = 0; j < 4; j++) h[j] = (n < 200) ? f2bf(W3[(k4 + j) * 200 + n]) : 0;
    *(ushortx4*)&W3t[n * 256 + k4] = h;
  } else if ((i -= 14336) < 7168) {        // W4t [128][224] <- W4[k][n], k<200
    int n = i / 56, k4 = (i - n * 56) * 4;
    ushortx4 h;
#pragma unroll
    for (int j = 0; j < 4; j++) h[j] = (k4 + j < 200) ? f2bf(W4[(k4 + j) * 128 + n]) : 0;
    *(ushortx4*)&W4t[n * 224 + k4] = h;
  } else if ((i -= 7168) < 128) {          // S = rowsum(K^2)
    float s = 0.f;
    for (int j = 0; j < 128; j++) { float v = K[i * 128 + j]; s += v * v; }
    S[i] = s;
  }
}

// ---- prefetch ks=0 weight fragments (issued BEFORE a barrier) ----
template <int KP, int CH>
static __device__ __forceinline__ void wpref(const unsigned short* __restrict__ wt,
                                             int tileRow0, int m, int qd, short8* wpre)
{
#pragma unroll
  for (int n = 0; n < CH; n++)
    wpre[n] = *(const short8*)&wt[(tileRow0 + n * 16 + m) * KP + qd * 8];
}

// ---- MFMA pass: CH col-tiles x 4 row-tiles (ALL 64 rows), K=KP; SINGLE pass
// per layer per wave (panel read once). lane (m,qd,reg) holds
// D[neuron = tile*16 + qd*4 + reg][row = rt*16 + m].
template <int KP, int CH>
static __device__ __forceinline__ void mfma_pass_pre(const unsigned short* __restrict__ wt,
                                                     int tileRow0, const unsigned short* actIn,
                                                     int sin, int m, int qd, floatx4* acc,
                                                     const short8* wpre)
{
#pragma unroll
  for (int i = 0; i < CH * 4; i++) acc[i] = {0.f, 0.f, 0.f, 0.f};
  short8 a[4];
#pragma unroll
  for (int rt = 0; rt < 4; rt++)
    a[rt] = *(const short8*)&actIn[(rt * 16 + m) * sin + qd * 8];
#pragma unroll
  for (int n = 0; n < CH; n++)
#pragma unroll
    for (int rt = 0; rt < 4; rt++)
      acc[n * 4 + rt] = __builtin_amdgcn_mfma_f32_16x16x32_bf16(wpre[n], a[rt], acc[n * 4 + rt], 0, 0, 0);
#pragma unroll
  for (int ks = 1; ks < KP / 32; ks++) {
#pragma unroll
    for (int rt = 0; rt < 4; rt++)
      a[rt] = *(const short8*)&actIn[(rt * 16 + m) * sin + ks * 32 + qd * 8];
#pragma unroll
    for (int n = 0; n < CH; n++) {
      short8 w = *(const short8*)&wt[(tileRow0 + n * 16 + m) * KP + ks * 32 + qd * 8];
#pragma unroll
      for (int rt = 0; rt < 4; rt++)
        acc[n * 4 + rt] = __builtin_amdgcn_mfma_f32_16x16x32_bf16(w, a[rt], acc[n * 4 + rt], 0, 0, 0);
    }
  }
}

// ---- epilogue for ONE tile: bias + relu, packed 8B stores ----
static __device__ __forceinline__ void epilogue_tile(const float* __restrict__ bias,
                                                     int colBase, int nreal,
                                                     unsigned short* actOut, int sout,
                                                     int m, int qd, const floatx4* acc)
{
  int col = colBase + qd * 4;
  float b0 = 0.f, b1 = 0.f, b2 = 0.f, b3 = 0.f;
  if (col < nreal) {
    float4 q = *(const float4*)(bias + col);
    b0 = q.x; b1 = q.y; b2 = q.z; b3 = q.w;
  }
#pragma unroll
  for (int rt = 0; rt < 4; rt++) {
    ushortx4 h = { f2bf(fmaxf(acc[rt][0] + b0, 0.f)),
                   f2bf(fmaxf(acc[rt][1] + b1, 0.f)),
                   f2bf(fmaxf(acc[rt][2] + b2, 0.f)),
                   f2bf(fmaxf(acc[rt][3] + b3, 0.f)) };
    *(ushortx4*)&actOut[(rt * 16 + m) * sout + col] = h;
  }
}

__shared__ unsigned short actA[BM * SA];
__shared__ unsigned short actB[BM * SB];
__shared__ float crosspart[3][BM];
__shared__ float part[BM][8];
__shared__ float qpart[BM][8];
__shared__ float linrow[BM];

// ---- fused layer worker: one CH-wide pass over emb panel; tiles < 8 are cross,
// tiles >= 8 are L1 (epilogue to actB). Branches are wave-uniform. ----
template <int CH>
static __device__ __forceinline__ void fused_layer(const unsigned short* __restrict__ Wc,
                                                   const float* __restrict__ b1,
                                                   int tilebase, int wave, int m, int qd,
                                                   const short8* wpre)
{
  floatx4 acc[CH * 4];
  mfma_pass_pre<128, CH>(Wc, tilebase * 16, actA, SA, m, qd, acc, wpre);
  float s[4] = {0.f, 0.f, 0.f, 0.f};
#pragma unroll
  for (int n = 0; n < CH; n++) {
    int tl = tilebase + n;
    if (tl < 8) {
#pragma unroll
      for (int rt = 0; rt < 4; rt++)
#pragma unroll
        for (int i = 0; i < 4; i++)
          s[rt] += acc[n * 4 + rt][i] * acc[n * 4 + rt][i];
    } else {
      epilogue_tile(b1, (tl - 8) * 16, 200, actB, SB, m, qd, &acc[n * 4]);
    }
  }
  if (tilebase < 8) {  // waves 0..2 hold cross tiles
#pragma unroll
    for (int rt = 0; rt < 4; rt++) {
      s[rt] += __shfl_xor(s[rt], 16, 64);
      s[rt] += __shfl_xor(s[rt], 32, 64);
    }
    if (qd == 0)
#pragma unroll
      for (int rt = 0; rt < 4; rt++)
        crosspart[wave][rt * 16 + m] = s[rt];
  }
}

// ---------------- fused main kernel ----------------
// 512 threads = 8 waves; each wave: ALL 64 rows x its tile share, ONE pass per layer
// (panel read once per wave per layer -> LDS traffic ~0.85 MB/block vs 1.48 R9).
__global__ __launch_bounds__(512)
void dfm_main(const int* __restrict__ uidx, const int* __restrict__ iidx,
              const float* __restrict__ uemb, const float* __restrict__ iemb,
              const float* __restrict__ linw, const float* __restrict__ linb,
              const float* __restrict__ b1, const float* __restrict__ b2,
              const float* __restrict__ b3, const float* __restrict__ b4,
              const float* __restrict__ W5, const float* __restrict__ b5,
              const float* __restrict__ S, const unsigned short* __restrict__ Wc,
              const unsigned short* __restrict__ W2t, const unsigned short* __restrict__ W3t,
              const unsigned short* __restrict__ W4t,
              float* __restrict__ out)
{
  const int t = threadIdx.x;
  const int lane = t & 63, wave = t >> 6;
  const int m = lane & 15, qd = lane >> 4;
  const int r = t >> 3, c = t & 7;

  // ---- gather + linear + q-partials ----
  {
    int g = blockIdx.x * BM + r;
    int u = uidx[g], it = iidx[g];
    const float* up = uemb + (long)u * EMBD + c * 8;
    const float* ip = iemb + (long)it * EMBD + c * 8;
    float qp = 0.f;
#pragma unroll
    for (int j = 0; j < 8; j += 4) {
      float4 f = *(const float4*)(up + j);
      int col = c * 8 + j;
      float4 sv = *(const float4*)(S + col);
      ushortx4 h = {f2bf(f.x), f2bf(f.y), f2bf(f.z), f2bf(f.w)};
      *(ushortx4*)&actA[r * SA + col] = h;
      qp += f.x * f.x * sv.x + f.y * f.y * sv.y + f.z * f.z * sv.z + f.w * f.w * sv.w;
    }
#pragma unroll
    for (int j = 0; j < 8; j += 4) {
      float4 f = *(const float4*)(ip + j);
      int col = 64 + c * 8 + j;
      float4 sv = *(const float4*)(S + col);
      ushortx4 h = {f2bf(f.x), f2bf(f.y), f2bf(f.z), f2bf(f.w)};
      *(ushortx4*)&actA[r * SA + col] = h;
      qp += f.x * f.x * sv.x + f.y * f.y * sv.y + f.z * f.z * sv.z + f.w * f.w * sv.w;
    }
    qpart[r][c] = qp;
    if (c == 0) linrow[r] = linw[u] + linw[HASH_BINS + it] + linb[0];
  }

  // fused-layer tile split over 22 tiles: {3,3,3,3,3,3,2,2}
  const int fbase = (wave < 6) ? wave * 3 : 18 + (wave - 6) * 2;
  short8 wpre[3];
  if (wave < 6) wpref<128, 3>(Wc, fbase * 16, m, qd, wpre);
  else          wpref<128, 2>(Wc, fbase * 16, m, qd, wpre);
  __syncthreads();  // B1: emb in actA

  // ---- fused layer (K=128): cross tiles 0-7 + L1 tiles 8-21 -> actB ----
  if (wave < 6) fused_layer<3>(Wc, b1, fbase, wave, m, qd, wpre);
  else          fused_layer<2>(Wc, b1, fbase, wave, m, qd, wpre);
  wpref<224, 2>(W2t, wave * 32, m, qd, wpre);
  __syncthreads();  // B2: L1 out (224, zero-padded) in actB

  // ---- W2: K=224, actB -> actA, 16 tiles, 2 per wave, ONE pass ----
  {
    floatx4 acc[8];
    mfma_pass_pre<224, 2>(W2t, wave * 32, actB, SB, m, qd, acc, wpre);
    epilogue_tile(b2, wave * 32, 256, actA, SA, m, qd, &acc[0]);
    epilogue_tile(b2, wave * 32 + 16, 256, actA, SA, m, qd, &acc[4]);
  }
  if (wave < 6) wpref<256, 2>(W3t, wave * 32, m, qd, wpre);
  else          wpref<256, 1>(W3t, (12 + (wave - 6)) * 16, m, qd, wpre);
  __syncthreads();  // B3: W2 out (256) in actA

  // ---- W3: K=256, actA -> actB, 14 tiles {2,2,2,2,2,2,1,1}, ONE pass ----
  if (wave < 6) {
    floatx4 acc[8];
    mfma_pass_pre<256, 2>(W3t, wave * 32, actA, SA, m, qd, acc, wpre);
    epilogue_tile(b3, wave * 32, 200, actB, SB, m, qd, &acc[0]);
    epilogue_tile(b3, wave * 32 + 16, 200, actB, SB, m, qd, &acc[4]);
  } else {
    floatx4 acc[4];
    int s0 = (12 + (wave - 6)) * 16;
    mfma_pass_pre<256, 1>(W3t, s0, actA, SA, m, qd, acc, wpre);
    epilogue_tile(b3, s0, 200, actB, SB, m, qd, acc);
  }
  wpref<224, 1>(W4t, wave * 16, m, qd, wpre);
  __syncthreads();  // B4: W3 out (224, zero-padded) in actB

  // ---- W4 + W5 fold in registers: wave owns neurons 16w..16w+15 ----
  {
    floatx4 acc[4];
    mfma_pass_pre<224, 1>(W4t, wave * 16, actB, SB, m, qd, acc, wpre);
    int nb = wave * 16 + qd * 4;
    float4 w5q = *(const float4*)(W5 + nb);
    float4 b4q = *(const float4*)(b4 + nb);
#pragma unroll
    for (int rt = 0; rt < 4; rt++) {
      float s = fmaxf(acc[rt][0] + b4q.x, 0.f) * w5q.x +
                fmaxf(acc[rt][1] + b4q.y, 0.f) * w5q.y +
                fmaxf(acc[rt][2] + b4q.z, 0.f) * w5q.z +
                fmaxf(acc[rt][3] + b4q.w, 0.f) * w5q.w;
      s += __shfl_xor(s, 16, 64);
      s += __shfl_xor(s, 32, 64);
      if (qd == 0) part[rt * 16 + m][wave] = s;
    }
  }
  __syncthreads();  // B5: partials ready

  // ---- combine + sigmoid ----
  if (t < BM) {
    float xk2 = crosspart[0][t] + crosspart[1][t] + crosspart[2][t];
    float qs = qpart[t][0] + qpart[t][1] + qpart[t][2] + qpart[t][3] +
               qpart[t][4] + qpart[t][5] + qpart[t][6] + qpart[t][7];
    float dnn = part[t][0] + part[t][1] + part[t][2] + part[t][3] +
                part[t][4] + part[t][5] + part[t][6] + part[t][7];
    const float inv = 0.5f / 128.f;
    float logit = linrow[t] + inv * (xk2 - qs) + dnn + b5[0];
    out[blockIdx.x * BM + t] = 1.f / (1.f + expf(-logit));
  }
}

extern "C" void kernel_launch(void* const* d_in, const int* in_sizes, int n_in,
                              void* d_out, int out_size, void* d_ws, size_t ws_size,
                              hipStream_t stream)
{
  const int*   uidx = (const int*)d_in[0];
  const int*   iidx = (const int*)d_in[1];
  const float* uemb = (const float*)d_in[2];
  const float* iemb = (const float*)d_in[3];
  const float* linw = (const float*)d_in[4];
  const float* linb = (const float*)d_in[5];
  const float* K    = (const float*)d_in[6];
  const float* W1   = (const float*)d_in[7];
  const float* b1   = (const float*)d_in[8];
  const float* W2   = (const float*)d_in[9];
  const float* b2   = (const float*)d_in[10];
  const float* W3   = (const float*)d_in[11];
  const float* b3   = (const float*)d_in[12];
  const float* W4   = (const float*)d_in[13];
  const float* b4   = (const float*)d_in[14];
  const float* W5   = (const float*)d_in[15];
  const float* b5   = (const float*)d_in[16];

  char* w = (char*)d_ws;
  float* S = (float*)w;
  unsigned short* Kt  = (unsigned short*)(w + 512);
  unsigned short* W1t = (unsigned short*)(w + 33280);
  unsigned short* W2t = (unsigned short*)(w + 90624);
  unsigned short* W3t = (unsigned short*)(w + 205312);
  unsigned short* W4t = (unsigned short*)(w + 320000);
  float* out = (float*)d_out;

  dfm_prep<<<185, 256, 0, stream>>>(K, W1, W2, W3, W4, S, Kt, W1t, W2t, W3t, W4t);
  dfm_main<<<BATCH / BM, 512, 0, stream>>>(uidx, iidx, uemb, iemb, linw, linb,
                                           b1, b2, b3, b4, W5, b5,
                                           S, Kt, W2t, W3t, W4t, out);
}